// Round 1
// baseline (4249.207 us; speedup 1.0000x reference)
//
#include <hip/hip_runtime.h>
#include <math.h>

#define SDIM 64
#define KDIM 16
#define ODIM 32
#define HDIM 30
#define TDIM 200
#define NDIM 512
#define NP 69761
#define EPSV 1e-6f
#define LOG2PIF 1.8378770664093453f

__device__ __forceinline__ float softplusf(float x) {
    return (x > 0.f) ? x + log1pf(expf(-x)) : log1pf(expf(x));
}
__device__ __forceinline__ float wave_max64(float v) {
#pragma unroll
    for (int off = 32; off; off >>= 1) v = fmaxf(v, __shfl_xor(v, off, 64));
    return v;
}
__device__ __forceinline__ float wave_sum64(float v) {
#pragma unroll
    for (int off = 32; off; off >>= 1) v += __shfl_xor(v, off, 64);
    return v;
}

// ---------------- kernel 1: per-n parameter transforms ----------------
__global__ __launch_bounds__(256) void transform_kernel(
    const float* __restrict__ theta, float* __restrict__ invstd,
    float* __restrict__ c0, float* __restrict__ ent,
    float* __restrict__ logC, float* __restrict__ Dws,
    float* __restrict__ pdfws)
{
    __shared__ float ls[SDIM * 33];
    const int n = blockIdx.x, tid = threadIdx.x;
    const float* thn = theta + (size_t)n * NP;

    for (int idx = tid; idx < SDIM * ODIM; idx += 256) {
        float x = thn[2048 + idx];
        float sp = softplusf(x) + EPSV;            // A_std
        invstd[(size_t)n * SDIM * ODIM + idx] = 1.f / sp;
        int s = idx >> 5, oo = idx & 31;
        ls[s * 33 + oo] = logf(sp);
    }
    __syncthreads();

    const int wave = tid >> 6, lane = tid & 63;
    if (wave == 0) {                                // c0, ent per state s
        float sum = 0.f;
#pragma unroll
        for (int oo = 0; oo < ODIM; ++oo) sum += ls[lane * 33 + oo];
        c0[n * SDIM + lane]  = -sum - 16.f * LOG2PIF;                 // -Σlogσ - O/2·log2π
        ent[n * SDIM + lane] =  sum + 32.f * (0.5f + 0.5f * LOG2PIF); // Σ(0.5+0.5log2π+logσ)
    } else if (wave == 1) {                         // log(C + eps)
        float x = thn[69632 + lane];
        float m = wave_max64(x);
        float e = expf(x - m);
        float ssum = wave_sum64(e);
        logC[n * SDIM + lane] = logf(e / ssum + EPSV);
    } else if (wave == 2) {                         // D = softmax(tD)
        float x = thn[69696 + lane];
        float m = wave_max64(x);
        float e = expf(x - m);
        float ssum = wave_sum64(e);
        Dws[n * SDIM + lane] = e / ssum;
    } else {                                        // truncated poisson pdf
        float tt = thn[69760];
        float tau = 60.f / (1.f + expf(-tt)) + 1.f;
        float p = 0.f;
        if (lane < HDIM)
            p = expf((float)lane * logf(tau) - tau - lgammaf((float)lane + 1.f));
        float ssum = wave_sum64(p);
        if (lane < HDIM) pdfws[n * HDIM + lane] = p / ssum;
    }
}

// ------------- kernel 2: per-row B softmax stats (lse) + reward r -------------
__global__ __launch_bounds__(256) void row_stats_kernel(
    const float* __restrict__ theta, const float* __restrict__ logC,
    const float* __restrict__ ent, float* __restrict__ lse,
    float* __restrict__ rws)
{
    const int gw = blockIdx.x * 4 + (threadIdx.x >> 6);  // global row (n,k,i)
    const int lane = threadIdx.x & 63;
    const int n = gw >> 10, rl = gw & 1023;
    float x = theta[(size_t)n * NP + 4096 + (size_t)rl * 64 + lane];
    float m = wave_max64(x);
    float e = expf(x - m);
    float ssum = wave_sum64(e);
    float Bj = e / ssum;
    float contrib = Bj * (logf(Bj + EPSV) - logC[n * SDIM + lane] + ent[n * SDIM + lane]);
    contrib = wave_sum64(contrib);
    if (lane == 0) {
        lse[gw] = m + logf(ssum);   // B[j] = exp(x[j] - lse)
        rws[gw] = -contrib;         // r = -kl - eh
    }
}

// ---------------- kernel 3: value iteration + time scan, one block per n ----------------
__global__ __launch_bounds__(256, 1) void main_kernel(
    const float* __restrict__ o, const int* __restrict__ a,
    const float* __restrict__ theta, const float* __restrict__ lse,
    const float* __restrict__ rws, const float* __restrict__ invstd,
    const float* __restrict__ c0g, const float* __restrict__ Dws,
    const float* __restrict__ pdfg,
    float* __restrict__ out_pi, float* __restrict__ out_b,
    float* __restrict__ out_lp)
{
    __shared__ float q[HDIM * KDIM * 65];   // padded stride 65
    __shared__ float r_s[KDIM * SDIM];
    __shared__ float lse_s[KDIM * SDIM];
    __shared__ float mean_s[SDIM * 33];
    __shared__ float istd_s[SDIM * 33];
    __shared__ float c0_s[SDIM];
    __shared__ float b_s[SDIM];
    __shared__ __align__(16) float v_s[SDIM];
    __shared__ float pdf_s[32];
    __shared__ float qb_s[HDIM * 17];       // padded stride 17
    __shared__ float wh_s[32];
    __shared__ float mh_s[32];
    __shared__ float part_s[4 * SDIM];
    __shared__ float z2_s[256];
    __shared__ float ot_s[ODIM];
    __shared__ float joint_s[SDIM];

    const int n = blockIdx.x, tid = threadIdx.x;
    const float* thn = theta + (size_t)n * NP;
    const float* Xn = thn + 4096;           // raw tB logits [k][i][j]

    // ---- stage per-n data into LDS ----
    for (int idx = tid; idx < SDIM * ODIM; idx += 256) {
        int s = idx >> 5, oo = idx & 31;
        mean_s[s * 33 + oo] = thn[idx];
        istd_s[s * 33 + oo] = invstd[(size_t)n * SDIM * ODIM + idx];
    }
    for (int idx = tid; idx < KDIM * SDIM; idx += 256) {
        r_s[idx]  = rws[(size_t)n * KDIM * SDIM + idx];
        lse_s[idx] = lse[(size_t)n * KDIM * SDIM + idx];
    }
    if (tid < SDIM) { c0_s[tid] = c0g[n * SDIM + tid]; b_s[tid] = Dws[n * SDIM + tid]; }
    if (tid < HDIM) pdf_s[tid] = pdfg[n * HDIM + tid];
    __syncthreads();

    // q[0] = r
    for (int idx = tid; idx < KDIM * SDIM; idx += 256)
        q[(idx >> 6) * 65 + (idx & 63)] = r_s[idx];
    __syncthreads();

    const int wave = tid >> 6, lane = tid & 63;
    const int sub = lane & 15, rq = lane >> 4;

    // ---- value iteration ----
    for (int h = 1; h < HDIM; ++h) {
        if (tid < SDIM) {                    // v[j] = logsumexp_k q[h-1][k][j]
            int base = (h - 1) * KDIM;
            float m = -1e30f;
#pragma unroll
            for (int k = 0; k < KDIM; ++k) m = fmaxf(m, q[(base + k) * 65 + tid]);
            float ssum = 0.f;
#pragma unroll
            for (int k = 0; k < KDIM; ++k) ssum += expf(q[(base + k) * 65 + tid] - m);
            v_s[tid] = m + logf(ssum);
        }
        __syncthreads();
        float v0 = v_s[sub * 4 + 0], v1 = v_s[sub * 4 + 1];
        float v2 = v_s[sub * 4 + 2], v3 = v_s[sub * 4 + 3];
#pragma unroll 4
        for (int it = 0; it < 64; ++it) {    // 1024 rows, 16-lane group per row
            int row = it * 16 + wave * 4 + rq;
            const float* xr = Xn + (size_t)row * 64 + sub * 4;
            float l = lse_s[row];
            float acc = expf(xr[0] - l) * v0 + expf(xr[1] - l) * v1
                      + expf(xr[2] - l) * v2 + expf(xr[3] - l) * v3;
            acc += __shfl_xor(acc, 1, 64);
            acc += __shfl_xor(acc, 2, 64);
            acc += __shfl_xor(acc, 4, 64);
            acc += __shfl_xor(acc, 8, 64);
            if (sub == 0)
                q[(h * KDIM + (row >> 6)) * 65 + (row & 63)] = r_s[row] + acc;
        }
        __syncthreads();
    }

    // ---- time loop ----
    for (int t = 0; t < TDIM; ++t) {
        // P0: emit b_seq, load o_t, qb[h,k] = <q[h,k,:], b>
        if (tid < SDIM) out_b[((size_t)t * NDIM + n) * SDIM + tid] = b_s[tid];
        if (tid < ODIM) ot_s[tid] = o[((size_t)t * NDIM + n) * ODIM + tid];
        const int at = a[t * NDIM + n];
        for (int p = tid; p < HDIM * KDIM; p += 256) {
            const float* qr = &q[p * 65];
            float acc = 0.f;
#pragma unroll
            for (int i = 0; i < SDIM; ++i) acc += qr[i] * b_s[i];
            qb_s[(p >> 4) * 17 + (p & 15)] = acc;
        }
        __syncthreads();

        // P1: per-h softmax stats; z^2 partials (4 threads per state)
        if (tid < HDIM) {
            float m = -1e30f;
#pragma unroll
            for (int k = 0; k < KDIM; ++k) m = fmaxf(m, qb_s[tid * 17 + k]);
            float ssum = 0.f;
#pragma unroll
            for (int k = 0; k < KDIM; ++k) ssum += expf(qb_s[tid * 17 + k] - m);
            wh_s[tid] = pdf_s[tid] / ssum;
            mh_s[tid] = m;
        }
        {
            int si = tid >> 2, g = tid & 3;
            float zacc = 0.f;
#pragma unroll
            for (int mm = 0; mm < 8; ++mm) {
                int oo = g * 8 + mm;
                float z = (ot_s[oo] - mean_s[si * 33 + oo]) * istd_s[si * 33 + oo];
                zacc += z * z;
            }
            z2_s[tid] = zacc;
        }
        __syncthreads();

        // P2: pi output; belief-transition partials with recomputed B_a
        if (tid < KDIM) {
            float acc = 0.f;
#pragma unroll
            for (int hh = 0; hh < HDIM; ++hh)
                acc += wh_s[hh] * expf(qb_s[hh * 17 + tid] - mh_s[hh]);
            out_pi[((size_t)t * NDIM + n) * KDIM + tid] = acc;
        }
        {
            const float* Xa = Xn + (size_t)at * SDIM * SDIM;
            const float* la = &lse_s[at * SDIM];
            float acc = 0.f;
#pragma unroll
            for (int ii = 0; ii < 16; ++ii) {
                int i = wave * 16 + ii;
                acc += expf(Xa[i * 64 + lane] - la[i]) * b_s[i];
            }
            part_s[wave * 64 + lane] = acc;
        }
        __syncthreads();

        // P3: joint[s] = log(s+eps) + c0 - 0.5*z2
        if (tid < SDIM) {
            float sv = part_s[tid] + part_s[64 + tid] + part_s[128 + tid] + part_s[192 + tid];
            float z2 = z2_s[tid * 4] + z2_s[tid * 4 + 1] + z2_s[tid * 4 + 2] + z2_s[tid * 4 + 3];
            joint_s[tid] = logf(sv + EPSV) + c0_s[tid] - 0.5f * z2;
        }
        __syncthreads();

        // P4: b <- softmax(joint); logp_o = logsumexp(joint)
        if (tid < SDIM) {
            float x = joint_s[tid];
            float m = wave_max64(x);
            float e = expf(x - m);
            float ssum = wave_sum64(e);
            b_s[tid] = e / ssum;
            if (tid == 0) out_lp[(size_t)t * NDIM + n] = m + logf(ssum);
        }
        __syncthreads();
    }
}

extern "C" void kernel_launch(void* const* d_in, const int* in_sizes, int n_in,
                              void* d_out, int out_size, void* d_ws, size_t ws_size,
                              hipStream_t stream) {
    (void)in_sizes; (void)n_in; (void)out_size; (void)ws_size;
    const float* o     = (const float*)d_in[0];
    const int*   a     = (const int*)d_in[1];
    const float* theta = (const float*)d_in[2];
    float* out = (float*)d_out;
    float* ws  = (float*)d_ws;

    float* lse    = ws;                                   // N*K*S
    float* rws    = lse    + (size_t)NDIM * KDIM * SDIM;  // N*K*S
    float* invstd = rws    + (size_t)NDIM * KDIM * SDIM;  // N*S*O
    float* c0     = invstd + (size_t)NDIM * SDIM * ODIM;  // N*S
    float* ent    = c0     + (size_t)NDIM * SDIM;         // N*S
    float* logC   = ent    + (size_t)NDIM * SDIM;         // N*S
    float* Dws    = logC   + (size_t)NDIM * SDIM;         // N*S
    float* pdfws  = Dws    + (size_t)NDIM * SDIM;         // N*H

    transform_kernel<<<NDIM, 256, 0, stream>>>(theta, invstd, c0, ent, logC, Dws, pdfws);
    row_stats_kernel<<<(NDIM * KDIM * SDIM) / 4, 256, 0, stream>>>(theta, logC, ent, lse, rws);
    main_kernel<<<NDIM, 256, 0, stream>>>(
        o, a, theta, lse, rws, invstd, c0, Dws, pdfws,
        out,
        out + (size_t)TDIM * NDIM * KDIM,
        out + (size_t)TDIM * NDIM * KDIM + (size_t)TDIM * NDIM * SDIM);
}

// Round 2
// 3409.616 us; speedup vs baseline: 1.2462x; 1.2462x over previous
//
#include <hip/hip_runtime.h>
#include <math.h>

#define SDIM 64
#define KDIM 16
#define ODIM 32
#define HDIM 30
#define TDIM 200
#define NDIM 512
#define NP 69761
#define EPSV 1e-6f
#define LOG2PIF 1.8378770664093453f
#define QSTR 68   // q row stride in floats: 68*4 = 272 B, 16B-aligned rows

__device__ __forceinline__ float softplusf(float x) {
    return (x > 0.f) ? x + log1pf(expf(-x)) : log1pf(expf(x));
}
__device__ __forceinline__ float wave_max64(float v) {
#pragma unroll
    for (int off = 32; off; off >>= 1) v = fmaxf(v, __shfl_xor(v, off, 64));
    return v;
}
__device__ __forceinline__ float wave_sum64(float v) {
#pragma unroll
    for (int off = 32; off; off >>= 1) v += __shfl_xor(v, off, 64);
    return v;
}

// ---------------- kernel 1: per-n parameter transforms ----------------
__global__ __launch_bounds__(256) void transform_kernel(
    const float* __restrict__ theta, float* __restrict__ invstd,
    float* __restrict__ c0, float* __restrict__ ent,
    float* __restrict__ logC, float* __restrict__ Dws,
    float* __restrict__ pdfws)
{
    __shared__ float ls[SDIM * 33];
    const int n = blockIdx.x, tid = threadIdx.x;
    const float* thn = theta + (size_t)n * NP;

    for (int idx = tid; idx < SDIM * ODIM; idx += 256) {
        float x = thn[2048 + idx];
        float sp = softplusf(x) + EPSV;            // A_std
        invstd[(size_t)n * SDIM * ODIM + idx] = 1.f / sp;
        int s = idx >> 5, oo = idx & 31;
        ls[s * 33 + oo] = logf(sp);
    }
    __syncthreads();

    const int wave = tid >> 6, lane = tid & 63;
    if (wave == 0) {                                // c0, ent per state s
        float sum = 0.f;
#pragma unroll
        for (int oo = 0; oo < ODIM; ++oo) sum += ls[lane * 33 + oo];
        c0[n * SDIM + lane]  = -sum - 16.f * LOG2PIF;
        ent[n * SDIM + lane] =  sum + 32.f * (0.5f + 0.5f * LOG2PIF);
    } else if (wave == 1) {                         // log(C + eps)
        float x = thn[69632 + lane];
        float m = wave_max64(x);
        float e = expf(x - m);
        float ssum = wave_sum64(e);
        logC[n * SDIM + lane] = logf(e / ssum + EPSV);
    } else if (wave == 2) {                         // D = softmax(tD)
        float x = thn[69696 + lane];
        float m = wave_max64(x);
        float e = expf(x - m);
        float ssum = wave_sum64(e);
        Dws[n * SDIM + lane] = e / ssum;
    } else {                                        // truncated poisson pdf
        float tt = thn[69760];
        float tau = 60.f / (1.f + expf(-tt)) + 1.f;
        float p = 0.f;
        if (lane < HDIM)
            p = expf((float)lane * logf(tau) - tau - lgammaf((float)lane + 1.f));
        float ssum = wave_sum64(p);
        if (lane < HDIM) pdfws[n * HDIM + lane] = p / ssum;
    }
}

// ------------- kernel 2: per-row B softmax stats (lse) + reward r -------------
__global__ __launch_bounds__(256) void row_stats_kernel(
    const float* __restrict__ theta, const float* __restrict__ logC,
    const float* __restrict__ ent, float* __restrict__ lse,
    float* __restrict__ rws)
{
    const int gw = blockIdx.x * 4 + (threadIdx.x >> 6);  // global row (n,k,i)
    const int lane = threadIdx.x & 63;
    const int n = gw >> 10, rl = gw & 1023;
    float x = theta[(size_t)n * NP + 4096 + (size_t)rl * 64 + lane];
    float m = wave_max64(x);
    float e = expf(x - m);
    float ssum = wave_sum64(e);
    float Bj = e / ssum;
    float contrib = Bj * (logf(Bj + EPSV) - logC[n * SDIM + lane] + ent[n * SDIM + lane]);
    contrib = wave_sum64(contrib);
    if (lane == 0) {
        lse[gw] = m + logf(ssum);
        rws[gw] = -contrib;
    }
}

// ------- kernel 3: VI + time scan, one 512-thread block per n, wave-specialized -------
__global__ __launch_bounds__(512, 1) void main_kernel(
    const float* __restrict__ o, const int* __restrict__ a,
    const float* __restrict__ theta, const float* __restrict__ lse,
    const float* __restrict__ rws, const float* __restrict__ invstd,
    const float* __restrict__ c0g, const float* __restrict__ Dws,
    const float* __restrict__ pdfg,
    float* __restrict__ out_pi, float* __restrict__ out_b,
    float* __restrict__ out_lp)
{
    __shared__ __align__(16) float q[HDIM * KDIM * QSTR];  // 130,560 B
    __shared__ float r_s[KDIM * SDIM];
    __shared__ float lse_s[KDIM * SDIM];
    __shared__ float mean_s[SDIM * 33];
    __shared__ float istd_s[SDIM * 33];
    __shared__ float c0_s[SDIM];
    __shared__ __align__(16) float b_s[2][SDIM];
    __shared__ float v_s[SDIM];
    __shared__ float pdf_s[32];
    __shared__ float qb_s[HDIM * 17];
    __shared__ float wh_s[32];
    __shared__ float mh_s[32];
    __shared__ float part_s[2][SDIM];
    __shared__ float z2_s[SDIM];
    __shared__ float ot_s[ODIM];

    const int n = blockIdx.x, tid = threadIdx.x;
    const float* thn = theta + (size_t)n * NP;
    const float* Xn = thn + 4096;           // raw tB logits [k][i][j]

    // ---- stage per-n data into LDS ----
    for (int idx = tid; idx < SDIM * ODIM; idx += 512) {
        int s = idx >> 5, oo = idx & 31;
        mean_s[s * 33 + oo] = thn[idx];
        istd_s[s * 33 + oo] = invstd[(size_t)n * SDIM * ODIM + idx];
    }
    for (int idx = tid; idx < KDIM * SDIM; idx += 512) {
        r_s[idx]   = rws[(size_t)n * KDIM * SDIM + idx];
        lse_s[idx] = lse[(size_t)n * KDIM * SDIM + idx];
    }
    if (tid < SDIM) { c0_s[tid] = c0g[n * SDIM + tid]; b_s[0][tid] = Dws[n * SDIM + tid]; }
    if (tid < HDIM) pdf_s[tid] = pdfg[n * HDIM + tid];
    __syncthreads();

    // q[0] = r
    for (int idx = tid; idx < KDIM * SDIM; idx += 512)
        q[(idx >> 6) * QSTR + (idx & 63)] = r_s[idx];
    __syncthreads();

    const int wave = tid >> 6, lane = tid & 63;
    const int sub = lane & 15, rq = lane >> 4;

    // ---- value iteration (all 8 waves) ----
    for (int h = 1; h < HDIM; ++h) {
        if (tid < SDIM) {                    // v[j] = logsumexp_k q[h-1][k][j]
            int base = (h - 1) * KDIM;
            float m = -1e30f;
#pragma unroll
            for (int k = 0; k < KDIM; ++k) m = fmaxf(m, q[(base + k) * QSTR + tid]);
            float ssum = 0.f;
#pragma unroll
            for (int k = 0; k < KDIM; ++k) ssum += expf(q[(base + k) * QSTR + tid] - m);
            v_s[tid] = m + logf(ssum);
        }
        __syncthreads();
        float v0 = v_s[sub * 4 + 0], v1 = v_s[sub * 4 + 1];
        float v2 = v_s[sub * 4 + 2], v3 = v_s[sub * 4 + 3];
#pragma unroll 4
        for (int it = 0; it < 32; ++it) {    // 1024 rows, 16-lane group per row
            int row = it * 32 + wave * 4 + rq;
            const float* xr = Xn + (size_t)row * 64 + sub * 4;
            float l = lse_s[row];
            float acc = expf(xr[0] - l) * v0 + expf(xr[1] - l) * v1
                      + expf(xr[2] - l) * v2 + expf(xr[3] - l) * v3;
            acc += __shfl_xor(acc, 1, 64);
            acc += __shfl_xor(acc, 2, 64);
            acc += __shfl_xor(acc, 4, 64);
            acc += __shfl_xor(acc, 8, 64);
            if (sub == 0)
                q[(h * KDIM + (row >> 6)) * QSTR + (row & 63)] = r_s[row] + acc;
        }
        __syncthreads();
    }

    // ---- time loop: waves 0-5 = policy side, waves 6-7 = belief side ----
    for (int t = 0; t < TDIM; ++t) {
        const int cur = t & 1, nxt = cur ^ 1;

        // ===== Phase I =====
        if (wave < 6) {
            // qb[h,k] = <q[h,k,:], b>, 16-lane group per row, 24 groups
            const int group = wave * 4 + rq;
            const float4 bv = *(const float4*)&b_s[cur][sub * 4];
#pragma unroll 5
            for (int r = group; r < HDIM * KDIM; r += 24) {
                const float4 qv = *(const float4*)&q[r * QSTR + sub * 4];
                float acc = qv.x * bv.x + qv.y * bv.y + qv.z * bv.z + qv.w * bv.w;
                acc += __shfl_xor(acc, 1, 64);
                acc += __shfl_xor(acc, 2, 64);
                acc += __shfl_xor(acc, 4, 64);
                acc += __shfl_xor(acc, 8, 64);
                if (sub == 0) qb_s[(r >> 4) * 17 + (r & 15)] = acc;
            }
        } else {
            const int at = a[t * NDIM + n];
            const float* Xa = Xn + (size_t)at * SDIM * SDIM;
            const float* la = &lse_s[at * SDIM];
            const int half = wave - 6;
            if (half == 0) {
                out_b[((size_t)t * NDIM + n) * SDIM + lane] = b_s[cur][lane];
            } else {
                if (lane < ODIM) ot_s[lane] = o[((size_t)t * NDIM + n) * ODIM + lane];
                float zacc = 0.f;
#pragma unroll
                for (int m = 0; m < ODIM; ++m) {
                    float z = (ot_s[m] - mean_s[lane * 33 + m]) * istd_s[lane * 33 + m];
                    zacc += z * z;
                }
                z2_s[lane] = zacc;
            }
            float acc = 0.f;
#pragma unroll
            for (int ii = 0; ii < 32; ++ii) {
                int i = half * 32 + ii;
                acc += expf(Xa[(size_t)i * 64 + lane] - la[i]) * b_s[cur][i];
            }
            part_s[half][lane] = acc;
        }
        __syncthreads();   // M

        // ===== Phase II =====
        if (wave < 4) {
            // per-h softmax stats over k: 8 lanes per h, 2 k per lane
            const int hh = tid >> 3, sl = tid & 7;
            if (hh < HDIM) {
                const int k0 = sl * 2;
                float q0 = qb_s[hh * 17 + k0], q1 = qb_s[hh * 17 + k0 + 1];
                float m = fmaxf(q0, q1);
                m = fmaxf(m, __shfl_xor(m, 1, 64));
                m = fmaxf(m, __shfl_xor(m, 2, 64));
                m = fmaxf(m, __shfl_xor(m, 4, 64));
                float e = expf(q0 - m) + expf(q1 - m);
                e += __shfl_xor(e, 1, 64);
                e += __shfl_xor(e, 2, 64);
                e += __shfl_xor(e, 4, 64);
                if (sl == 0) { wh_s[hh] = pdf_s[hh] / e; mh_s[hh] = m; }
            }
        } else if (wave == 6) {
            // joint, belief softmax, logp_o
            float sv = part_s[0][lane] + part_s[1][lane];
            float joint = logf(sv + EPSV) + c0_s[lane] - 0.5f * z2_s[lane];
            float m = wave_max64(joint);
            float e = expf(joint - m);
            float ssum = wave_sum64(e);
            b_s[nxt][lane] = e / ssum;
            if (lane == 0) out_lp[(size_t)t * NDIM + n] = m + logf(ssum);
        }
        __syncthreads();   // S

        // ===== Phase III: pi (waves 4-5) =====
        if (wave == 4 || wave == 5) {
            const int l = tid - 256;          // 0..127
            const int k = l >> 3, sl = l & 7;
            float acc = 0.f;
#pragma unroll
            for (int j = 0; j < 4; ++j) {
                int hh = sl + 8 * j;
                if (hh < HDIM)
                    acc += wh_s[hh] * expf(qb_s[hh * 17 + k] - mh_s[hh]);
            }
            acc += __shfl_xor(acc, 1, 64);
            acc += __shfl_xor(acc, 2, 64);
            acc += __shfl_xor(acc, 4, 64);
            if (sl == 0) out_pi[((size_t)t * NDIM + n) * KDIM + k] = acc;
        }
        __syncthreads();   // E
    }
}

extern "C" void kernel_launch(void* const* d_in, const int* in_sizes, int n_in,
                              void* d_out, int out_size, void* d_ws, size_t ws_size,
                              hipStream_t stream) {
    (void)in_sizes; (void)n_in; (void)out_size; (void)ws_size;
    const float* o     = (const float*)d_in[0];
    const int*   a     = (const int*)d_in[1];
    const float* theta = (const float*)d_in[2];
    float* out = (float*)d_out;
    float* ws  = (float*)d_ws;

    float* lse    = ws;                                   // N*K*S
    float* rws    = lse    + (size_t)NDIM * KDIM * SDIM;  // N*K*S
    float* invstd = rws    + (size_t)NDIM * KDIM * SDIM;  // N*S*O
    float* c0     = invstd + (size_t)NDIM * SDIM * ODIM;  // N*S
    float* ent    = c0     + (size_t)NDIM * SDIM;         // N*S
    float* logC   = ent    + (size_t)NDIM * SDIM;         // N*S
    float* Dws    = logC   + (size_t)NDIM * SDIM;         // N*S
    float* pdfws  = Dws    + (size_t)NDIM * SDIM;         // N*H

    transform_kernel<<<NDIM, 256, 0, stream>>>(theta, invstd, c0, ent, logC, Dws, pdfws);
    row_stats_kernel<<<(NDIM * KDIM * SDIM) / 4, 256, 0, stream>>>(theta, logC, ent, lse, rws);
    main_kernel<<<NDIM, 512, 0, stream>>>(
        o, a, theta, lse, rws, invstd, c0, Dws, pdfws,
        out,
        out + (size_t)TDIM * NDIM * KDIM,
        out + (size_t)TDIM * NDIM * KDIM + (size_t)TDIM * NDIM * SDIM);
}

// Round 4
// 1558.591 us; speedup vs baseline: 2.7263x; 2.1876x over previous
//
#include <hip/hip_runtime.h>
#include <math.h>

#define SDIM 64
#define KDIM 16
#define ODIM 32
#define HDIM 30
#define TDIM 200
#define NDIM 512
#define NP 69761
#define EPSV 1e-6f
#define LOG2PIF 1.8378770664093453f

__device__ __forceinline__ float softplusf(float x) {
    return (x > 0.f) ? x + log1pf(expf(-x)) : log1pf(expf(x));
}
__device__ __forceinline__ float wave_max64(float v) {
#pragma unroll
    for (int off = 32; off; off >>= 1) v = fmaxf(v, __shfl_xor(v, off, 64));
    return v;
}
__device__ __forceinline__ float wave_sum64(float v) {
#pragma unroll
    for (int off = 32; off; off >>= 1) v += __shfl_xor(v, off, 64);
    return v;
}

// ---------------- kernel 1: per-n parameter transforms ----------------
__global__ __launch_bounds__(256) void transform_kernel(
    const float* __restrict__ theta, float* __restrict__ invstd,
    float* __restrict__ c0, float* __restrict__ ent,
    float* __restrict__ logC, float* __restrict__ Dws,
    float* __restrict__ pdfws)
{
    __shared__ float ls[SDIM * 33];
    const int n = blockIdx.x, tid = threadIdx.x;
    const float* thn = theta + (size_t)n * NP;

    for (int idx = tid; idx < SDIM * ODIM; idx += 256) {
        float x = thn[2048 + idx];
        float sp = softplusf(x) + EPSV;            // A_std
        invstd[(size_t)n * SDIM * ODIM + idx] = 1.f / sp;
        int s = idx >> 5, oo = idx & 31;
        ls[s * 33 + oo] = logf(sp);
    }
    __syncthreads();

    const int wave = tid >> 6, lane = tid & 63;
    if (wave == 0) {                                // c0, ent per state s
        float sum = 0.f;
#pragma unroll
        for (int oo = 0; oo < ODIM; ++oo) sum += ls[lane * 33 + oo];
        c0[n * SDIM + lane]  = -sum - 16.f * LOG2PIF;
        ent[n * SDIM + lane] =  sum + 32.f * (0.5f + 0.5f * LOG2PIF);
    } else if (wave == 1) {                         // log(C + eps)
        float x = thn[69632 + lane];
        float m = wave_max64(x);
        float e = expf(x - m);
        float ssum = wave_sum64(e);
        logC[n * SDIM + lane] = logf(e / ssum + EPSV);
    } else if (wave == 2) {                         // D = softmax(tD)
        float x = thn[69696 + lane];
        float m = wave_max64(x);
        float e = expf(x - m);
        float ssum = wave_sum64(e);
        Dws[n * SDIM + lane] = e / ssum;
    } else {                                        // truncated poisson pdf
        float tt = thn[69760];
        float tau = 60.f / (1.f + expf(-tt)) + 1.f;
        float p = 0.f;
        if (lane < HDIM)
            p = expf((float)lane * logf(tau) - tau - lgammaf((float)lane + 1.f));
        float ssum = wave_sum64(p);
        if (lane < HDIM) pdfws[n * HDIM + lane] = p / ssum;
    }
}

// ------------- kernel 2: per-row B softmax stats (lse) + reward r -------------
__global__ __launch_bounds__(256) void row_stats_kernel(
    const float* __restrict__ theta, const float* __restrict__ logC,
    const float* __restrict__ ent, float* __restrict__ lse,
    float* __restrict__ rws)
{
    const int gw = blockIdx.x * 4 + (threadIdx.x >> 6);  // global row (n,k,i)
    const int lane = threadIdx.x & 63;
    const int n = gw >> 10, rl = gw & 1023;
    float x = theta[(size_t)n * NP + 4096 + (size_t)rl * 64 + lane];
    float m = wave_max64(x);
    float e = expf(x - m);
    float ssum = wave_sum64(e);
    float Bj = e / ssum;
    float contrib = Bj * (logf(Bj + EPSV) - logC[n * SDIM + lane] + ent[n * SDIM + lane]);
    contrib = wave_sum64(contrib);
    if (lane == 0) {
        lse[gw] = m + logf(ssum);
        rws[gw] = -contrib;
    }
}

// ------- kernel 3: belief time-scan, one block per n, software-pipelined -------
// waves 1-7: B_a matvec rows (prefetch next t's exp(B_a) during wave0's softmax)
// wave 0:   z2 (during matvec) + joint + softmax + logp_o
__global__ __launch_bounds__(512, 1) void belief_kernel(
    const float* __restrict__ o, const int* __restrict__ a,
    const float* __restrict__ theta, const float* __restrict__ lse,
    const float* __restrict__ invstd, const float* __restrict__ c0g,
    const float* __restrict__ Dws,
    float* __restrict__ out_b, float* __restrict__ out_lp)
{
    __shared__ float o_s[TDIM * ODIM];      // 25.6 KB
    __shared__ int   a_s[TDIM];
    __shared__ float mean_s[SDIM * 33];
    __shared__ float istd_s[SDIM * 33];
    __shared__ float lseA[KDIM * SDIM];
    __shared__ float c0_s[SDIM];
    __shared__ float b_s[2][SDIM];
    __shared__ float part_s[7][68];

    const int n = blockIdx.x, tid = threadIdx.x;
    const int wave = tid >> 6, lane = tid & 63;
    const float* thn = theta + (size_t)n * NP;
    const float* Xn  = thn + 4096;

    for (int idx = tid; idx < TDIM * ODIM; idx += 512) {
        int t = idx >> 5;
        o_s[idx] = o[((size_t)t * NDIM + n) * ODIM + (idx & 31)];
    }
    if (tid < TDIM) a_s[tid] = a[tid * NDIM + n];
    for (int idx = tid; idx < SDIM * ODIM; idx += 512) {
        int s = idx >> 5, oo = idx & 31;
        mean_s[s * 33 + oo] = thn[idx];
        istd_s[s * 33 + oo] = invstd[(size_t)n * SDIM * ODIM + idx];
    }
    for (int idx = tid; idx < KDIM * SDIM; idx += 512)
        lseA[idx] = lse[(size_t)n * KDIM * SDIM + idx];
    if (tid < SDIM) { c0_s[tid] = c0g[n * SDIM + tid]; b_s[0][tid] = Dws[n * SDIM + tid]; }
    __syncthreads();

    const int rbase = (wave >= 1) ? (wave - 1) * 10 : 0;
    const int nrow  = (wave >= 1) ? ((SDIM - rbase) < 10 ? (SDIM - rbase) : 10) : 0;

    float er[10];
    // prologue: prefetch exp(B_a) rows for t = 0
    if (wave >= 1) {
        const int at = a_s[0];
        const float* Xa = Xn + (size_t)at * SDIM * SDIM;
        const float* la = lseA + at * SDIM;
#pragma unroll
        for (int ii = 0; ii < 10; ++ii)
            if (ii < nrow) er[ii] = __expf(Xa[(size_t)(rbase + ii) * SDIM + lane] - la[rbase + ii]);
    }

    for (int t = 0; t < TDIM; ++t) {
        const int cur = t & 1, nxt = cur ^ 1;
        float z2 = 0.f;
        if (wave >= 1) {
            float acc = 0.f;
#pragma unroll
            for (int ii = 0; ii < 10; ++ii)
                if (ii < nrow) acc += er[ii] * b_s[cur][rbase + ii];
            part_s[wave - 1][lane] = acc;
            if (wave == 1) out_b[((size_t)t * NDIM + n) * SDIM + lane] = b_s[cur][lane];
        } else {
            const float* om = &o_s[t * ODIM];
#pragma unroll
            for (int m = 0; m < ODIM; ++m) {
                float z = (om[m] - mean_s[lane * 33 + m]) * istd_s[lane * 33 + m];
                z2 += z * z;
            }
        }
        __syncthreads();   // A: parts ready
        if (wave == 0) {
            float sv = 0.f;
#pragma unroll
            for (int w = 0; w < 7; ++w) sv += part_s[w][lane];
            float joint = __logf(sv + EPSV) + c0_s[lane] - 0.5f * z2;
            float m = wave_max64(joint);
            float e = __expf(joint - m);
            float ssum = wave_sum64(e);
            b_s[nxt][lane] = e / ssum;
            if (lane == 0) out_lp[(size_t)t * NDIM + n] = m + __logf(ssum);
        } else if (t + 1 < TDIM) {
            const int at = a_s[t + 1];
            const float* Xa = Xn + (size_t)at * SDIM * SDIM;
            const float* la = lseA + at * SDIM;
#pragma unroll
            for (int ii = 0; ii < 10; ++ii)
                if (ii < nrow) er[ii] = __expf(Xa[(size_t)(rbase + ii) * SDIM + lane] - la[rbase + ii]);
        }
        __syncthreads();   // B: b_s[nxt] ready
    }
}

// ------- kernel 4: VI with B-in-registers + policy (q stays in LDS) -------
__global__ __launch_bounds__(512, 1) void vi_policy_kernel(
    const float* __restrict__ theta, const float* __restrict__ lse,
    const float* __restrict__ rws, const float* __restrict__ pdfg,
    const float* __restrict__ out_b_g, float* __restrict__ out_pi)
{
    __shared__ __align__(16) float q_s[HDIM * KDIM * 68];  // 130,560 B
    __shared__ float r_s[KDIM * SDIM];
    __shared__ float lse_s[KDIM * SDIM];
    __shared__ __align__(16) float v_s[SDIM];
    __shared__ __align__(16) float b_lds[32 * 68];
    __shared__ float pdf_s[32];

    const int n = blockIdx.x, tid = threadIdx.x;
    const int wave = tid >> 6, lane = tid & 63;
    const int sub = lane & 15, rq = lane >> 4;
    const float* Xn = theta + (size_t)n * NP + 4096;

    for (int idx = tid; idx < KDIM * SDIM; idx += 512) {
        r_s[idx]   = rws[(size_t)n * KDIM * SDIM + idx];
        lse_s[idx] = lse[(size_t)n * KDIM * SDIM + idx];
    }
    if (tid < HDIM) pdf_s[tid] = pdfg[n * HDIM + tid];
    __syncthreads();

    // q[0] = r
    for (int idx = tid; idx < KDIM * SDIM; idx += 512)
        q_s[(idx >> 6) * 68 + (idx & 63)] = r_s[idx];

    // ---- load B fragments into registers: exp(x - lse), one-time ----
    // thread covers rows it*32 + wave*4 + rq (32 rows), cols sub*4..sub*4+3
    float4 breg[32];
    {
#pragma unroll
        for (int it = 0; it < 32; ++it) {
            const int row = it * 32 + wave * 4 + rq;
            const float* xr = Xn + (size_t)row * SDIM + sub * 4;
            const float l = lse_s[row];
            float4 v;
            v.x = __expf(xr[0] - l);
            v.y = __expf(xr[1] - l);
            v.z = __expf(xr[2] - l);
            v.w = __expf(xr[3] - l);
            breg[it] = v;
        }
    }
    __syncthreads();

    // ---- value iteration from registers ----
#pragma unroll 1
    for (int h = 1; h < HDIM; ++h) {
        if (tid < SDIM) {
            const int base = (h - 1) * KDIM;
            float m = -1e30f;
#pragma unroll
            for (int k = 0; k < KDIM; ++k) m = fmaxf(m, q_s[(base + k) * 68 + tid]);
            float ssum = 0.f;
#pragma unroll
            for (int k = 0; k < KDIM; ++k) ssum += __expf(q_s[(base + k) * 68 + tid] - m);
            v_s[tid] = m + __logf(ssum);
        }
        __syncthreads();
        const float4 v4 = *(const float4*)&v_s[sub * 4];
#pragma unroll
        for (int it = 0; it < 32; ++it) {
            const int row = it * 32 + wave * 4 + rq;
            float acc = breg[it].x * v4.x + breg[it].y * v4.y
                      + breg[it].z * v4.z + breg[it].w * v4.w;
            acc += __shfl_xor(acc, 1, 64);
            acc += __shfl_xor(acc, 2, 64);
            acc += __shfl_xor(acc, 4, 64);
            acc += __shfl_xor(acc, 8, 64);
            if (sub == 0)
                q_s[(h * KDIM + (row >> 6)) * 68 + (row & 63)] = r_s[row] + acc;
        }
        __syncthreads();
    }

    // ---- policy: threads (tc=t-local 0..31, kk 0..15), b_t in registers ----
    const int tc = tid >> 4, kk = tid & 15;
#pragma unroll 1
    for (int tch = 0; tch < 7; ++tch) {
        const int t0 = tch * 32;
        const int nt = (TDIM - t0) < 32 ? (TDIM - t0) : 32;
        if (tid < nt * 16) {
            const int tt = tid >> 4, jq = tid & 15;
            const float4 bv = *(const float4*)&out_b_g[(((size_t)(t0 + tt)) * NDIM + n) * SDIM + jq * 4];
            *(float4*)&b_lds[tt * 68 + jq * 4] = bv;
        }
        __syncthreads();
        if (tc < nt) {
            float4 bq[16];
#pragma unroll
            for (int jq = 0; jq < 16; ++jq)
                bq[jq] = *(const float4*)&b_lds[tc * 68 + jq * 4];
            float pik = 0.f;
#pragma unroll 1
            for (int h = 0; h < HDIM; ++h) {
                const float* qr = &q_s[(h * KDIM + kk) * 68];
                float ax = 0.f, ay = 0.f, az = 0.f, aw = 0.f;
#pragma unroll
                for (int jq = 0; jq < 16; ++jq) {
                    const float4 qv = *(const float4*)&qr[jq * 4];
                    ax += qv.x * bq[jq].x; ay += qv.y * bq[jq].y;
                    az += qv.z * bq[jq].z; aw += qv.w * bq[jq].w;
                }
                float qb = (ax + ay) + (az + aw);
                float m = qb;
                m = fmaxf(m, __shfl_xor(m, 1, 64));
                m = fmaxf(m, __shfl_xor(m, 2, 64));
                m = fmaxf(m, __shfl_xor(m, 4, 64));
                m = fmaxf(m, __shfl_xor(m, 8, 64));
                float e = __expf(qb - m);
                float S = e;
                S += __shfl_xor(S, 1, 64);
                S += __shfl_xor(S, 2, 64);
                S += __shfl_xor(S, 4, 64);
                S += __shfl_xor(S, 8, 64);
                pik += pdf_s[h] * e / S;
            }
            out_pi[(((size_t)(t0 + tc)) * NDIM + n) * KDIM + kk] = pik;
        }
        __syncthreads();
    }
}

extern "C" void kernel_launch(void* const* d_in, const int* in_sizes, int n_in,
                              void* d_out, int out_size, void* d_ws, size_t ws_size,
                              hipStream_t stream) {
    (void)in_sizes; (void)n_in; (void)out_size; (void)ws_size;
    const float* o     = (const float*)d_in[0];
    const int*   a     = (const int*)d_in[1];
    const float* theta = (const float*)d_in[2];
    float* out = (float*)d_out;
    float* ws  = (float*)d_ws;

    float* lse    = ws;                                   // N*K*S
    float* rws    = lse    + (size_t)NDIM * KDIM * SDIM;  // N*K*S
    float* invstd = rws    + (size_t)NDIM * KDIM * SDIM;  // N*S*O
    float* c0     = invstd + (size_t)NDIM * SDIM * ODIM;  // N*S
    float* ent    = c0     + (size_t)NDIM * SDIM;         // N*S
    float* logC   = ent    + (size_t)NDIM * SDIM;         // N*S
    float* Dws    = logC   + (size_t)NDIM * SDIM;         // N*S
    float* pdfws  = Dws    + (size_t)NDIM * SDIM;         // N*H

    float* out_pi = out;
    float* out_b  = out + (size_t)TDIM * NDIM * KDIM;
    float* out_lp = out + (size_t)TDIM * NDIM * KDIM + (size_t)TDIM * NDIM * SDIM;

    transform_kernel<<<NDIM, 256, 0, stream>>>(theta, invstd, c0, ent, logC, Dws, pdfws);
    row_stats_kernel<<<(NDIM * KDIM * SDIM) / 4, 256, 0, stream>>>(theta, logC, ent, lse, rws);
    belief_kernel<<<NDIM, 512, 0, stream>>>(o, a, theta, lse, invstd, c0, Dws, out_b, out_lp);
    vi_policy_kernel<<<NDIM, 512, 0, stream>>>(theta, lse, rws, pdfws, out_b, out_pi);
}

// Round 5
// 988.215 us; speedup vs baseline: 4.2999x; 1.5772x over previous
//
#include <hip/hip_runtime.h>
#include <math.h>

#define SDIM 64
#define KDIM 16
#define ODIM 32
#define HDIM 30
#define TDIM 200
#define NDIM 512
#define NP 69761
#define EPSV 1e-6f
#define LOG2PIF 1.8378770664093453f

__device__ __forceinline__ float softplusf(float x) {
    return (x > 0.f) ? x + log1pf(expf(-x)) : log1pf(expf(x));
}
__device__ __forceinline__ float wave_max64(float v) {
#pragma unroll
    for (int off = 32; off; off >>= 1) v = fmaxf(v, __shfl_xor(v, off, 64));
    return v;
}
__device__ __forceinline__ float wave_sum64(float v) {
#pragma unroll
    for (int off = 32; off; off >>= 1) v += __shfl_xor(v, off, 64);
    return v;
}
// barrier that waits only on LDS ops — leaves global loads/stores in flight
// (plain __syncthreads drains vmcnt(0), putting HBM latency on the barrier)
__device__ __forceinline__ void bar_lds() {
    asm volatile("s_waitcnt lgkmcnt(0)\n\ts_barrier" ::: "memory");
}

// ---------------- kernel 1: per-n parameter transforms ----------------
__global__ __launch_bounds__(256) void transform_kernel(
    const float* __restrict__ theta, float* __restrict__ invstd,
    float* __restrict__ c0, float* __restrict__ ent,
    float* __restrict__ logC, float* __restrict__ Dws,
    float* __restrict__ pdfws)
{
    __shared__ float ls[SDIM * 33];
    const int n = blockIdx.x, tid = threadIdx.x;
    const float* thn = theta + (size_t)n * NP;

    for (int idx = tid; idx < SDIM * ODIM; idx += 256) {
        float x = thn[2048 + idx];
        float sp = softplusf(x) + EPSV;            // A_std
        invstd[(size_t)n * SDIM * ODIM + idx] = 1.f / sp;
        int s = idx >> 5, oo = idx & 31;
        ls[s * 33 + oo] = logf(sp);
    }
    __syncthreads();

    const int wave = tid >> 6, lane = tid & 63;
    if (wave == 0) {                                // c0, ent per state s
        float sum = 0.f;
#pragma unroll
        for (int oo = 0; oo < ODIM; ++oo) sum += ls[lane * 33 + oo];
        c0[n * SDIM + lane]  = -sum - 16.f * LOG2PIF;
        ent[n * SDIM + lane] =  sum + 32.f * (0.5f + 0.5f * LOG2PIF);
    } else if (wave == 1) {                         // log(C + eps)
        float x = thn[69632 + lane];
        float m = wave_max64(x);
        float e = expf(x - m);
        float ssum = wave_sum64(e);
        logC[n * SDIM + lane] = logf(e / ssum + EPSV);
    } else if (wave == 2) {                         // D = softmax(tD)
        float x = thn[69696 + lane];
        float m = wave_max64(x);
        float e = expf(x - m);
        float ssum = wave_sum64(e);
        Dws[n * SDIM + lane] = e / ssum;
    } else {                                        // truncated poisson pdf
        float tt = thn[69760];
        float tau = 60.f / (1.f + expf(-tt)) + 1.f;
        float p = 0.f;
        if (lane < HDIM)
            p = expf((float)lane * logf(tau) - tau - lgammaf((float)lane + 1.f));
        float ssum = wave_sum64(p);
        if (lane < HDIM) pdfws[n * HDIM + lane] = p / ssum;
    }
}

// ------------- kernel 2: per-row B softmax stats (lse) + reward r -------------
__global__ __launch_bounds__(256) void row_stats_kernel(
    const float* __restrict__ theta, const float* __restrict__ logC,
    const float* __restrict__ ent, float* __restrict__ lse,
    float* __restrict__ rws)
{
    const int gw = blockIdx.x * 4 + (threadIdx.x >> 6);  // global row (n,k,i)
    const int lane = threadIdx.x & 63;
    const int n = gw >> 10, rl = gw & 1023;
    float x = theta[(size_t)n * NP + 4096 + (size_t)rl * 64 + lane];
    float m = wave_max64(x);
    float e = expf(x - m);
    float ssum = wave_sum64(e);
    float Bj = e / ssum;
    float contrib = Bj * (logf(Bj + EPSV) - logC[n * SDIM + lane] + ent[n * SDIM + lane]);
    contrib = wave_sum64(contrib);
    if (lane == 0) {
        lse[gw] = m + logf(ssum);
        rws[gw] = -contrib;
    }
}

// z2 partial for step TT_ into buffer BUF_ (waves 1..4, 8 obs each)
#define Z2PART(TT_, BUF_) do {                                                 \
    const int ob_ = (wave - 1) * 8;                                            \
    const float* om_ = &o_s[(TT_) * ODIM + ob_];                               \
    float zz_ = 0.f;                                                           \
    _Pragma("unroll")                                                          \
    for (int j_ = 0; j_ < 8; ++j_) {                                           \
        float z_ = (om_[j_] - mean_s[lane * 33 + ob_ + j_])                    \
                 * istd_s[lane * 33 + ob_ + j_];                               \
        zz_ += z_ * z_;                                                        \
    }                                                                          \
    z2p_s[BUF_][wave - 1][lane] = zz_;                                         \
} while (0)

// one belief time-step; RAW_ = register buffer holding logits for step T_+1
#define BSTEP(T_, RAW_) do {                                                   \
    const int cur_ = (T_) & 1, nxt_ = cur_ ^ 1;                                \
    if (wave >= 1) {                                                           \
        float acc_ = 0.f;                                                      \
        _Pragma("unroll")                                                      \
        for (int ii = 0; ii < 10; ++ii)                                        \
            if (ii < nrow) acc_ += er[ii] * b_s[cur_][rbase + ii];             \
        part_s[wave - 1][lane] = acc_;                                         \
        if (wave == 6) out_b[((size_t)(T_) * NDIM + n) * SDIM + lane] = b_s[cur_][lane]; \
    }                                                                          \
    bar_lds();                                                                 \
    if (wave == 0) {                                                           \
        float sv_ = part_s[0][lane] + part_s[1][lane] + part_s[2][lane]        \
                  + part_s[3][lane] + part_s[4][lane] + part_s[5][lane]        \
                  + part_s[6][lane];                                           \
        float z2_ = z2p_s[cur_][0][lane] + z2p_s[cur_][1][lane]                \
                  + z2p_s[cur_][2][lane] + z2p_s[cur_][3][lane];               \
        float joint_ = __logf(sv_ + EPSV) + c0_s[lane] - 0.5f * z2_;           \
        float m_ = wave_max64(joint_);                                         \
        float e_ = __expf(joint_ - m_);                                        \
        float ss_ = wave_sum64(e_);                                            \
        b_s[nxt_][lane] = e_ / ss_;                                            \
        if (lane == 0) out_lp[(size_t)(T_) * NDIM + n] = m_ + __logf(ss_);     \
    } else {                                                                   \
        if ((T_) + 1 < TDIM) {                                                 \
            const int an_ = a_s[(T_) + 1];                                     \
            const float* ln_ = lseA + an_ * SDIM;                              \
            _Pragma("unroll")                                                  \
            for (int ii = 0; ii < 10; ++ii)                                    \
                if (ii < nrow) er[ii] = __expf(RAW_[ii] - ln_[rbase + ii]);    \
            if (wave <= 4) Z2PART((T_) + 1, nxt_);                             \
        }                                                                      \
        const int tl_ = ((T_) + 3 < TDIM) ? (T_) + 3 : TDIM - 1;               \
        const int a3_ = a_s[tl_];                                              \
        const float* X3_ = Xn + (size_t)a3_ * SDIM * SDIM;                     \
        _Pragma("unroll")                                                      \
        for (int ii = 0; ii < 10; ++ii)                                        \
            if (ii < nrow) RAW_[ii] = X3_[(size_t)(rbase + ii) * SDIM + lane]; \
    }                                                                          \
    bar_lds();                                                                 \
} while (0)

// ------- kernel 3: belief time-scan, one block per n, depth-2 pipelined -------
__global__ __launch_bounds__(512) void belief_kernel(
    const float* __restrict__ o, const int* __restrict__ a,
    const float* __restrict__ theta, const float* __restrict__ lse,
    const float* __restrict__ invstd, const float* __restrict__ c0g,
    const float* __restrict__ Dws,
    float* __restrict__ out_b, float* __restrict__ out_lp)
{
    __shared__ float o_s[TDIM * ODIM];      // 25.6 KB
    __shared__ int   a_s[TDIM];
    __shared__ float mean_s[SDIM * 33];
    __shared__ float istd_s[SDIM * 33];
    __shared__ float lseA[KDIM * SDIM];
    __shared__ float c0_s[SDIM];
    __shared__ float b_s[2][SDIM];
    __shared__ float part_s[7][68];
    __shared__ float z2p_s[2][4][SDIM];

    const int n = blockIdx.x, tid = threadIdx.x;
    const int wave = tid >> 6, lane = tid & 63;
    const float* thn = theta + (size_t)n * NP;
    const float* Xn  = thn + 4096;

    for (int idx = tid; idx < TDIM * ODIM; idx += 512) {
        int t = idx >> 5;
        o_s[idx] = o[((size_t)t * NDIM + n) * ODIM + (idx & 31)];
    }
    if (tid < TDIM) a_s[tid] = a[tid * NDIM + n];
    for (int idx = tid; idx < SDIM * ODIM; idx += 512) {
        int s = idx >> 5, oo = idx & 31;
        mean_s[s * 33 + oo] = thn[idx];
        istd_s[s * 33 + oo] = invstd[(size_t)n * SDIM * ODIM + idx];
    }
    for (int idx = tid; idx < KDIM * SDIM; idx += 512)
        lseA[idx] = lse[(size_t)n * KDIM * SDIM + idx];
    if (tid < SDIM) { c0_s[tid] = c0g[n * SDIM + tid]; b_s[0][tid] = Dws[n * SDIM + tid]; }
    __syncthreads();

    const int rbase = (wave >= 1) ? (wave - 1) * 10 : 0;
    const int nrow  = (wave >= 1) ? ((SDIM - rbase) < 10 ? (SDIM - rbase) : 10) : 0;

    float er[10], raw0[10], raw1[10];
    // prologue: er for t=0; raw0 = logits(t=1); raw1 = logits(t=2); z2p for t=0
    if (wave >= 1) {
        const int a0 = a_s[0];
        const float* X0 = Xn + (size_t)a0 * SDIM * SDIM;
        const float* l0 = lseA + a0 * SDIM;
#pragma unroll
        for (int ii = 0; ii < 10; ++ii)
            if (ii < nrow) er[ii] = __expf(X0[(size_t)(rbase + ii) * SDIM + lane] - l0[rbase + ii]);
        const int a1 = a_s[1];
        const float* X1 = Xn + (size_t)a1 * SDIM * SDIM;
#pragma unroll
        for (int ii = 0; ii < 10; ++ii)
            if (ii < nrow) raw0[ii] = X1[(size_t)(rbase + ii) * SDIM + lane];
        const int a2 = a_s[2];
        const float* X2 = Xn + (size_t)a2 * SDIM * SDIM;
#pragma unroll
        for (int ii = 0; ii < 10; ++ii)
            if (ii < nrow) raw1[ii] = X2[(size_t)(rbase + ii) * SDIM + lane];
        if (wave <= 4) Z2PART(0, 0);
    }
    __syncthreads();

#pragma unroll 1
    for (int t = 0; t < TDIM; t += 2) {
        BSTEP(t, raw0);
        BSTEP(t + 1, raw1);
    }
}

// ------- kernel 4: VI with B-in-registers + policy (q stays in LDS) -------
__global__ __launch_bounds__(512) void vi_policy_kernel(
    const float* __restrict__ theta, const float* __restrict__ lse,
    const float* __restrict__ rws, const float* __restrict__ pdfg,
    const float* __restrict__ out_b_g, float* __restrict__ out_pi)
{
    __shared__ __align__(16) float q_s[HDIM * KDIM * 68];  // 130,560 B
    __shared__ float r_s[KDIM * SDIM];
    __shared__ float lse_s[KDIM * SDIM];
    __shared__ __align__(16) float v_s[SDIM];
    __shared__ __align__(16) float b_lds[64 * 68];         // 17,408 B
    __shared__ float pdf_s[32];

    const int n = blockIdx.x, tid = threadIdx.x;
    const int wave = tid >> 6, lane = tid & 63;
    const int sub = lane & 15, rq = lane >> 4;
    const float* Xn = theta + (size_t)n * NP + 4096;

    for (int idx = tid; idx < KDIM * SDIM; idx += 512) {
        r_s[idx]   = rws[(size_t)n * KDIM * SDIM + idx];
        lse_s[idx] = lse[(size_t)n * KDIM * SDIM + idx];
    }
    if (tid < HDIM) pdf_s[tid] = pdfg[n * HDIM + tid];
    __syncthreads();

    // q[0] = r
    for (int idx = tid; idx < KDIM * SDIM; idx += 512)
        q_s[(idx >> 6) * 68 + (idx & 63)] = r_s[idx];

    // ---- load B fragments into registers: exp(x - lse), one-time ----
    float4 breg[32];
    {
#pragma unroll
        for (int it = 0; it < 32; ++it) {
            const int row = it * 32 + wave * 4 + rq;
            const float* xr = Xn + (size_t)row * SDIM + sub * 4;
            const float l = lse_s[row];
            float4 v;
            v.x = __expf(xr[0] - l);
            v.y = __expf(xr[1] - l);
            v.z = __expf(xr[2] - l);
            v.w = __expf(xr[3] - l);
            breg[it] = v;
        }
    }
    bar_lds();

    // ---- value iteration from registers ----
#pragma unroll 1
    for (int h = 1; h < HDIM; ++h) {
        if (tid < SDIM) {
            const int base = (h - 1) * KDIM;
            float m = -1e30f;
#pragma unroll
            for (int k = 0; k < KDIM; ++k) m = fmaxf(m, q_s[(base + k) * 68 + tid]);
            float ssum = 0.f;
#pragma unroll
            for (int k = 0; k < KDIM; ++k) ssum += __expf(q_s[(base + k) * 68 + tid] - m);
            v_s[tid] = m + __logf(ssum);
        }
        bar_lds();
        const float4 v4 = *(const float4*)&v_s[sub * 4];
#pragma unroll
        for (int it = 0; it < 32; ++it) {
            const int row = it * 32 + wave * 4 + rq;
            float acc = breg[it].x * v4.x + breg[it].y * v4.y
                      + breg[it].z * v4.z + breg[it].w * v4.w;
            acc += __shfl_xor(acc, 1, 64);
            acc += __shfl_xor(acc, 2, 64);
            acc += __shfl_xor(acc, 4, 64);
            acc += __shfl_xor(acc, 8, 64);
            if (sub == 0)
                q_s[(h * KDIM + (row >> 6)) * 68 + (row & 63)] = r_s[row] + acc;
        }
        bar_lds();
    }

    // ---- policy: 64-t chunks, thread (tc,kk) handles t0+tc and t0+32+tc ----
    const int tc = tid >> 4, kk = tid & 15;
#pragma unroll 1
    for (int t0 = 0; t0 < TDIM; t0 += 64) {
        const int nt = (TDIM - t0) < 64 ? (TDIM - t0) : 64;
        for (int idx = tid; idx < nt * 16; idx += 512) {
            const int row = idx >> 4, jq = idx & 15;
            *(float4*)&b_lds[row * 68 + jq * 4] =
                *(const float4*)&out_b_g[(((size_t)(t0 + row)) * NDIM + n) * SDIM + jq * 4];
        }
        bar_lds();
        const bool vA = tc < nt, vB = (tc + 32) < nt;
        float4 bqA[16], bqB[16];
        if (vA) {
#pragma unroll
            for (int jq = 0; jq < 16; ++jq)
                bqA[jq] = *(const float4*)&b_lds[tc * 68 + jq * 4];
        }
        if (vB) {
#pragma unroll
            for (int jq = 0; jq < 16; ++jq)
                bqB[jq] = *(const float4*)&b_lds[(tc + 32) * 68 + jq * 4];
        }
        float pikA = 0.f, pikB = 0.f;
#pragma unroll 1
        for (int h = 0; h < HDIM; ++h) {
            const float* qr = &q_s[(h * KDIM + kk) * 68];
            float aA = 0.f, aB = 0.f;
#pragma unroll
            for (int jq = 0; jq < 16; ++jq) {
                const float4 qv = *(const float4*)&qr[jq * 4];
                if (vA) aA += qv.x * bqA[jq].x + qv.y * bqA[jq].y
                            + qv.z * bqA[jq].z + qv.w * bqA[jq].w;
                if (vB) aB += qv.x * bqB[jq].x + qv.y * bqB[jq].y
                            + qv.z * bqB[jq].z + qv.w * bqB[jq].w;
            }
            float mA = aA, mB = aB;
            mA = fmaxf(mA, __shfl_xor(mA, 1, 64));
            mA = fmaxf(mA, __shfl_xor(mA, 2, 64));
            mA = fmaxf(mA, __shfl_xor(mA, 4, 64));
            mA = fmaxf(mA, __shfl_xor(mA, 8, 64));
            mB = fmaxf(mB, __shfl_xor(mB, 1, 64));
            mB = fmaxf(mB, __shfl_xor(mB, 2, 64));
            mB = fmaxf(mB, __shfl_xor(mB, 4, 64));
            mB = fmaxf(mB, __shfl_xor(mB, 8, 64));
            float eA = __expf(aA - mA), eB = __expf(aB - mB);
            float SA = eA, SB = eB;
            SA += __shfl_xor(SA, 1, 64);
            SA += __shfl_xor(SA, 2, 64);
            SA += __shfl_xor(SA, 4, 64);
            SA += __shfl_xor(SA, 8, 64);
            SB += __shfl_xor(SB, 1, 64);
            SB += __shfl_xor(SB, 2, 64);
            SB += __shfl_xor(SB, 4, 64);
            SB += __shfl_xor(SB, 8, 64);
            const float ph = pdf_s[h];
            pikA += ph * eA / SA;
            pikB += ph * eB / SB;
        }
        if (vA) out_pi[(((size_t)(t0 + tc)) * NDIM + n) * KDIM + kk] = pikA;
        if (vB) out_pi[(((size_t)(t0 + 32 + tc)) * NDIM + n) * KDIM + kk] = pikB;
        bar_lds();
    }
}

extern "C" void kernel_launch(void* const* d_in, const int* in_sizes, int n_in,
                              void* d_out, int out_size, void* d_ws, size_t ws_size,
                              hipStream_t stream) {
    (void)in_sizes; (void)n_in; (void)out_size; (void)ws_size;
    const float* o     = (const float*)d_in[0];
    const int*   a     = (const int*)d_in[1];
    const float* theta = (const float*)d_in[2];
    float* out = (float*)d_out;
    float* ws  = (float*)d_ws;

    float* lse    = ws;                                   // N*K*S
    float* rws    = lse    + (size_t)NDIM * KDIM * SDIM;  // N*K*S
    float* invstd = rws    + (size_t)NDIM * KDIM * SDIM;  // N*S*O
    float* c0     = invstd + (size_t)NDIM * SDIM * ODIM;  // N*S
    float* ent    = c0     + (size_t)NDIM * SDIM;         // N*S
    float* logC   = ent    + (size_t)NDIM * SDIM;         // N*S
    float* Dws    = logC   + (size_t)NDIM * SDIM;         // N*S
    float* pdfws  = Dws    + (size_t)NDIM * SDIM;         // N*H

    float* out_pi = out;
    float* out_b  = out + (size_t)TDIM * NDIM * KDIM;
    float* out_lp = out + (size_t)TDIM * NDIM * KDIM + (size_t)TDIM * NDIM * SDIM;

    transform_kernel<<<NDIM, 256, 0, stream>>>(theta, invstd, c0, ent, logC, Dws, pdfws);
    row_stats_kernel<<<(NDIM * KDIM * SDIM) / 4, 256, 0, stream>>>(theta, logC, ent, lse, rws);
    belief_kernel<<<NDIM, 512, 0, stream>>>(o, a, theta, lse, invstd, c0, Dws, out_b, out_lp);
    vi_policy_kernel<<<NDIM, 512, 0, stream>>>(theta, lse, rws, pdfws, out_b, out_pi);
}

// Round 6
// 760.002 us; speedup vs baseline: 5.5910x; 1.3003x over previous
//
#include <hip/hip_runtime.h>
#include <math.h>

#define SDIM 64
#define KDIM 16
#define ODIM 32
#define HDIM 30
#define TDIM 200
#define NDIM 512
#define NP 69761
#define EPSV 1e-6f
#define LOG2PIF 1.8378770664093453f

__device__ __forceinline__ float softplusf(float x) {
    return (x > 0.f) ? x + log1pf(expf(-x)) : log1pf(expf(x));
}
__device__ __forceinline__ float wave_max64(float v) {
#pragma unroll
    for (int off = 32; off; off >>= 1) v = fmaxf(v, __shfl_xor(v, off, 64));
    return v;
}
__device__ __forceinline__ float wave_sum64(float v) {
#pragma unroll
    for (int off = 32; off; off >>= 1) v += __shfl_xor(v, off, 64);
    return v;
}
// barrier that waits only on LDS ops — leaves global loads/stores in flight
__device__ __forceinline__ void bar_lds() {
    asm volatile("s_waitcnt lgkmcnt(0)\n\ts_barrier" ::: "memory");
}

// ---------------- kernel 1: per-n parameter transforms ----------------
__global__ __launch_bounds__(256) void transform_kernel(
    const float* __restrict__ theta, float* __restrict__ invstd,
    float* __restrict__ c0, float* __restrict__ ent,
    float* __restrict__ logC, float* __restrict__ Dws,
    float* __restrict__ pdfws)
{
    __shared__ float ls[SDIM * 33];
    const int n = blockIdx.x, tid = threadIdx.x;
    const float* thn = theta + (size_t)n * NP;

    for (int idx = tid; idx < SDIM * ODIM; idx += 256) {
        float x = thn[2048 + idx];
        float sp = softplusf(x) + EPSV;            // A_std
        invstd[(size_t)n * SDIM * ODIM + idx] = 1.f / sp;
        int s = idx >> 5, oo = idx & 31;
        ls[s * 33 + oo] = logf(sp);
    }
    __syncthreads();

    const int wave = tid >> 6, lane = tid & 63;
    if (wave == 0) {                                // c0, ent per state s
        float sum = 0.f;
#pragma unroll
        for (int oo = 0; oo < ODIM; ++oo) sum += ls[lane * 33 + oo];
        c0[n * SDIM + lane]  = -sum - 16.f * LOG2PIF;
        ent[n * SDIM + lane] =  sum + 32.f * (0.5f + 0.5f * LOG2PIF);
    } else if (wave == 1) {                         // log(C + eps)
        float x = thn[69632 + lane];
        float m = wave_max64(x);
        float e = expf(x - m);
        float ssum = wave_sum64(e);
        logC[n * SDIM + lane] = logf(e / ssum + EPSV);
    } else if (wave == 2) {                         // D = softmax(tD)
        float x = thn[69696 + lane];
        float m = wave_max64(x);
        float e = expf(x - m);
        float ssum = wave_sum64(e);
        Dws[n * SDIM + lane] = e / ssum;
    } else {                                        // truncated poisson pdf
        float tt = thn[69760];
        float tau = 60.f / (1.f + expf(-tt)) + 1.f;
        float p = 0.f;
        if (lane < HDIM)
            p = expf((float)lane * logf(tau) - tau - lgammaf((float)lane + 1.f));
        float ssum = wave_sum64(p);
        if (lane < HDIM) pdfws[n * HDIM + lane] = p / ssum;
    }
}

// ------------- kernel 2: per-row B softmax stats (lse) + reward r -------------
__global__ __launch_bounds__(256) void row_stats_kernel(
    const float* __restrict__ theta, const float* __restrict__ logC,
    const float* __restrict__ ent, float* __restrict__ lse,
    float* __restrict__ rws)
{
    const int gw = blockIdx.x * 4 + (threadIdx.x >> 6);  // global row (n,k,i)
    const int lane = threadIdx.x & 63;
    const int n = gw >> 10, rl = gw & 1023;
    float x = theta[(size_t)n * NP + 4096 + (size_t)rl * 64 + lane];
    float m = wave_max64(x);
    float e = expf(x - m);
    float ssum = wave_sum64(e);
    float Bj = e / ssum;
    float contrib = Bj * (logf(Bj + EPSV) - logC[n * SDIM + lane] + ent[n * SDIM + lane]);
    contrib = wave_sum64(contrib);
    if (lane == 0) {
        lse[gw] = m + logf(ssum);
        rws[gw] = -contrib;
    }
}

// z2 partial for step TT_ into buffer BUF_ (waves 1..4, 8 obs each)
#define Z2PART(TT_, BUF_) do {                                                 \
    const int ob_ = (wave - 1) * 8;                                            \
    const float* om_ = &o_s[(TT_) * ODIM + ob_];                               \
    float zz_ = 0.f;                                                           \
    _Pragma("unroll")                                                          \
    for (int j_ = 0; j_ < 8; ++j_) {                                           \
        float z_ = (om_[j_] - mean_s[lane * 33 + ob_ + j_])                    \
                 * istd_s[lane * 33 + ob_ + j_];                               \
        zz_ += z_ * z_;                                                        \
    }                                                                          \
    z2p_s[BUF_][wave - 1][lane] = zz_;                                         \
} while (0)

// one belief time-step; RAW_ = register buffer holding logits for step T_+1
#define BSTEP(T_, RAW_) do {                                                   \
    const int cur_ = (T_) & 1, nxt_ = cur_ ^ 1;                                \
    if (wave >= 1) {                                                           \
        float acc_ = 0.f;                                                      \
        _Pragma("unroll")                                                      \
        for (int ii = 0; ii < 10; ++ii)                                        \
            if (ii < nrow) acc_ += er[ii] * b_s[cur_][rbase + ii];             \
        part_s[wave - 1][lane] = acc_;                                         \
        if (wave == 6) out_b[((size_t)(T_) * NDIM + n) * SDIM + lane] = b_s[cur_][lane]; \
    }                                                                          \
    bar_lds();                                                                 \
    if (wave == 0) {                                                           \
        float sv_ = part_s[0][lane] + part_s[1][lane] + part_s[2][lane]        \
                  + part_s[3][lane] + part_s[4][lane] + part_s[5][lane]        \
                  + part_s[6][lane];                                           \
        float z2_ = z2p_s[cur_][0][lane] + z2p_s[cur_][1][lane]                \
                  + z2p_s[cur_][2][lane] + z2p_s[cur_][3][lane];               \
        float joint_ = __logf(sv_ + EPSV) + c0_s[lane] - 0.5f * z2_;           \
        float m_ = wave_max64(joint_);                                         \
        float e_ = __expf(joint_ - m_);                                        \
        float ss_ = wave_sum64(e_);                                            \
        b_s[nxt_][lane] = e_ / ss_;                                            \
        if (lane == 0) out_lp[(size_t)(T_) * NDIM + n] = m_ + __logf(ss_);     \
    } else {                                                                   \
        if ((T_) + 1 < TDIM) {                                                 \
            const int an_ = a_s[(T_) + 1];                                     \
            const float* ln_ = lseA + an_ * SDIM;                              \
            _Pragma("unroll")                                                  \
            for (int ii = 0; ii < 10; ++ii)                                    \
                if (ii < nrow) er[ii] = __expf(RAW_[ii] - ln_[rbase + ii]);    \
            if (wave <= 4) Z2PART((T_) + 1, nxt_);                             \
        }                                                                      \
        const int tl_ = ((T_) + 3 < TDIM) ? (T_) + 3 : TDIM - 1;               \
        const int a3_ = a_s[tl_];                                              \
        const float* X3_ = Xn + (size_t)a3_ * SDIM * SDIM;                     \
        _Pragma("unroll")                                                      \
        for (int ii = 0; ii < 10; ++ii)                                        \
            if (ii < nrow) RAW_[ii] = X3_[(size_t)(rbase + ii) * SDIM + lane]; \
    }                                                                          \
    bar_lds();                                                                 \
} while (0)

// ------- kernel 3: belief time-scan, one block per n, depth-2 pipelined -------
__global__ __launch_bounds__(512) void belief_kernel(
    const float* __restrict__ o, const int* __restrict__ a,
    const float* __restrict__ theta, const float* __restrict__ lse,
    const float* __restrict__ invstd, const float* __restrict__ c0g,
    const float* __restrict__ Dws,
    float* __restrict__ out_b, float* __restrict__ out_lp)
{
    __shared__ float o_s[TDIM * ODIM];      // 25.6 KB
    __shared__ int   a_s[TDIM];
    __shared__ float mean_s[SDIM * 33];
    __shared__ float istd_s[SDIM * 33];
    __shared__ float lseA[KDIM * SDIM];
    __shared__ float c0_s[SDIM];
    __shared__ float b_s[2][SDIM];
    __shared__ float part_s[7][68];
    __shared__ float z2p_s[2][4][SDIM];

    const int n = blockIdx.x, tid = threadIdx.x;
    const int wave = tid >> 6, lane = tid & 63;
    const float* thn = theta + (size_t)n * NP;
    const float* Xn  = thn + 4096;

    for (int idx = tid; idx < TDIM * ODIM; idx += 512) {
        int t = idx >> 5;
        o_s[idx] = o[((size_t)t * NDIM + n) * ODIM + (idx & 31)];
    }
    if (tid < TDIM) a_s[tid] = a[tid * NDIM + n];
    for (int idx = tid; idx < SDIM * ODIM; idx += 512) {
        int s = idx >> 5, oo = idx & 31;
        mean_s[s * 33 + oo] = thn[idx];
        istd_s[s * 33 + oo] = invstd[(size_t)n * SDIM * ODIM + idx];
    }
    for (int idx = tid; idx < KDIM * SDIM; idx += 512)
        lseA[idx] = lse[(size_t)n * KDIM * SDIM + idx];
    if (tid < SDIM) { c0_s[tid] = c0g[n * SDIM + tid]; b_s[0][tid] = Dws[n * SDIM + tid]; }
    __syncthreads();

    const int rbase = (wave >= 1) ? (wave - 1) * 10 : 0;
    const int nrow  = (wave >= 1) ? ((SDIM - rbase) < 10 ? (SDIM - rbase) : 10) : 0;

    float er[10], raw0[10], raw1[10];
    if (wave >= 1) {
        const int a0 = a_s[0];
        const float* X0 = Xn + (size_t)a0 * SDIM * SDIM;
        const float* l0 = lseA + a0 * SDIM;
#pragma unroll
        for (int ii = 0; ii < 10; ++ii)
            if (ii < nrow) er[ii] = __expf(X0[(size_t)(rbase + ii) * SDIM + lane] - l0[rbase + ii]);
        const int a1 = a_s[1];
        const float* X1 = Xn + (size_t)a1 * SDIM * SDIM;
#pragma unroll
        for (int ii = 0; ii < 10; ++ii)
            if (ii < nrow) raw0[ii] = X1[(size_t)(rbase + ii) * SDIM + lane];
        const int a2 = a_s[2];
        const float* X2 = Xn + (size_t)a2 * SDIM * SDIM;
#pragma unroll
        for (int ii = 0; ii < 10; ++ii)
            if (ii < nrow) raw1[ii] = X2[(size_t)(rbase + ii) * SDIM + lane];
        if (wave <= 4) Z2PART(0, 0);
    }
    __syncthreads();

#pragma unroll 1
    for (int t = 0; t < TDIM; t += 2) {
        BSTEP(t, raw0);
        BSTEP(t + 1, raw1);
    }
}

// ------- kernel 4a: VI, thread-owns-row, q streamed to global workspace -------
__global__ __launch_bounds__(512) void vi_kernel(
    const float* __restrict__ theta, const float* __restrict__ lse,
    const float* __restrict__ rws, float* __restrict__ q_ws)
{
    __shared__ float q_lds[KDIM * 68];
    __shared__ __align__(16) float v_lds[68];
    const int n = blockIdx.x, tid = threadIdx.x;
    const float* Xn = theta + (size_t)n * NP + 4096;

    const float l0  = lse[(size_t)n * 1024 + tid];
    const float l1  = lse[(size_t)n * 1024 + 512 + tid];
    const float rr0 = rws[(size_t)n * 1024 + tid];
    const float rr1 = rws[(size_t)n * 1024 + 512 + tid];

    float4 er0[16], er1[16];
    {
        const float* X0 = Xn + (size_t)tid * 64;
        const float* X1 = Xn + (size_t)(512 + tid) * 64;
#pragma unroll
        for (int j = 0; j < 16; ++j) {
            float4 x = *(const float4*)(X0 + j * 4);
            er0[j] = make_float4(__expf(x.x - l0), __expf(x.y - l0),
                                 __expf(x.z - l0), __expf(x.w - l0));
            float4 y = *(const float4*)(X1 + j * 4);
            er1[j] = make_float4(__expf(y.x - l1), __expf(y.y - l1),
                                 __expf(y.z - l1), __expf(y.w - l1));
        }
    }

    float qr0 = rr0, qr1 = rr1;
    float* qw = q_ws + (size_t)n * HDIM * 1024;
    const int kq0 = tid >> 6, iq = tid & 63;
    qw[tid] = qr0;
    qw[512 + tid] = qr1;
    q_lds[kq0 * 68 + iq] = qr0;
    q_lds[(8 + kq0) * 68 + iq] = qr1;
    __syncthreads();

#pragma unroll 1
    for (int h = 1; h < HDIM; ++h) {
        if (tid < 64) {
            float m = -1e30f;
#pragma unroll
            for (int k = 0; k < KDIM; ++k) m = fmaxf(m, q_lds[k * 68 + tid]);
            float s = 0.f;
#pragma unroll
            for (int k = 0; k < KDIM; ++k) s += __expf(q_lds[k * 68 + tid] - m);
            v_lds[tid] = m + __logf(s);
        }
        bar_lds();
        float a0x = 0.f, a0y = 0.f, a0z = 0.f, a0w = 0.f;
        float a1x = 0.f, a1y = 0.f, a1z = 0.f, a1w = 0.f;
#pragma unroll
        for (int jq = 0; jq < 16; ++jq) {
            const float4 v4 = *(const float4*)&v_lds[jq * 4];
            a0x += er0[jq].x * v4.x; a0y += er0[jq].y * v4.y;
            a0z += er0[jq].z * v4.z; a0w += er0[jq].w * v4.w;
            a1x += er1[jq].x * v4.x; a1y += er1[jq].y * v4.y;
            a1z += er1[jq].z * v4.z; a1w += er1[jq].w * v4.w;
        }
        qr0 = rr0 + ((a0x + a0y) + (a0z + a0w));
        qr1 = rr1 + ((a1x + a1y) + (a1z + a1w));
        qw[(size_t)h * 1024 + tid] = qr0;
        qw[(size_t)h * 1024 + 512 + tid] = qr1;
        q_lds[kq0 * 68 + iq] = qr0;
        q_lds[(8 + kq0) * 68 + iq] = qr1;
        bar_lds();
    }
}

// ------- kernel 4b: policy, streaming per-h q tiles, 32-t chunks -------
__global__ __launch_bounds__(256) void policy_kernel(
    const float* __restrict__ q_ws, const float* __restrict__ out_b_g,
    const float* __restrict__ pdfg, float* __restrict__ out_pi)
{
    __shared__ __align__(16) float qt[2][KDIM * 68];
    __shared__ __align__(16) float bt[32 * 68];
    __shared__ float pdf_s[32];

    const int n = blockIdx.y, tch = blockIdx.x, tid = threadIdx.x;
    const int t0 = tch * 32;
    const int nt = (TDIM - t0) < 32 ? (TDIM - t0) : 32;
    const int tc = tid >> 4, kk = tid & 15;
    const float* qn = q_ws + (size_t)n * HDIM * 1024;

    for (int idx = tid; idx < 32 * 16; idx += 256) {
        const int row = idx >> 4, jq = idx & 15;
        float4 bv = make_float4(0.f, 0.f, 0.f, 0.f);
        if (row < nt)
            bv = *(const float4*)&out_b_g[(((size_t)(t0 + row)) * NDIM + n) * SDIM + jq * 4];
        *(float4*)&bt[row * 68 + jq * 4] = bv;
    }
    if (tid < HDIM) pdf_s[tid] = pdfg[n * HDIM + tid];
    {
        const float4 qv = *(const float4*)&qn[tid * 4];
        *(float4*)&qt[0][(tid >> 4) * 68 + (tid & 15) * 4] = qv;
    }
    __syncthreads();

    float4 bqA[16], bqB[16];
#pragma unroll
    for (int jq = 0; jq < 16; ++jq) {
        bqA[jq] = *(const float4*)&bt[tc * 68 + jq * 4];
        bqB[jq] = *(const float4*)&bt[(tc + 16) * 68 + jq * 4];
    }

    float pikA = 0.f, pikB = 0.f;
    float4 pre = *(const float4*)&qn[1024 + tid * 4];

#pragma unroll 1
    for (int h = 0; h < HDIM; ++h) {
        const float* qr = &qt[h & 1][kk * 68];
        float aAx = 0.f, aAy = 0.f, aAz = 0.f, aAw = 0.f;
        float aBx = 0.f, aBy = 0.f, aBz = 0.f, aBw = 0.f;
#pragma unroll
        for (int jq = 0; jq < 16; ++jq) {
            const float4 q4 = *(const float4*)&qr[jq * 4];
            aAx += q4.x * bqA[jq].x; aAy += q4.y * bqA[jq].y;
            aAz += q4.z * bqA[jq].z; aAw += q4.w * bqA[jq].w;
            aBx += q4.x * bqB[jq].x; aBy += q4.y * bqB[jq].y;
            aBz += q4.z * bqB[jq].z; aBw += q4.w * bqB[jq].w;
        }
        float aA = (aAx + aAy) + (aAz + aAw);
        float aB = (aBx + aBy) + (aBz + aBw);
        float mA = aA, mB = aB;
        mA = fmaxf(mA, __shfl_xor(mA, 1, 64));
        mA = fmaxf(mA, __shfl_xor(mA, 2, 64));
        mA = fmaxf(mA, __shfl_xor(mA, 4, 64));
        mA = fmaxf(mA, __shfl_xor(mA, 8, 64));
        mB = fmaxf(mB, __shfl_xor(mB, 1, 64));
        mB = fmaxf(mB, __shfl_xor(mB, 2, 64));
        mB = fmaxf(mB, __shfl_xor(mB, 4, 64));
        mB = fmaxf(mB, __shfl_xor(mB, 8, 64));
        float eA = __expf(aA - mA), eB = __expf(aB - mB);
        float SA = eA, SB = eB;
        SA += __shfl_xor(SA, 1, 64);
        SA += __shfl_xor(SA, 2, 64);
        SA += __shfl_xor(SA, 4, 64);
        SA += __shfl_xor(SA, 8, 64);
        SB += __shfl_xor(SB, 1, 64);
        SB += __shfl_xor(SB, 2, 64);
        SB += __shfl_xor(SB, 4, 64);
        SB += __shfl_xor(SB, 8, 64);
        const float ph = pdf_s[h];
        pikA += ph * eA / SA;
        pikB += ph * eB / SB;
        bar_lds();
        if (h + 1 < HDIM) {
            *(float4*)&qt[(h + 1) & 1][(tid >> 4) * 68 + (tid & 15) * 4] = pre;
            if (h + 2 < HDIM)
                pre = *(const float4*)&qn[(size_t)(h + 2) * 1024 + tid * 4];
        }
        bar_lds();
    }
    if (tc < nt)
        out_pi[(((size_t)(t0 + tc)) * NDIM + n) * KDIM + kk] = pikA;
    if (tc + 16 < nt)
        out_pi[(((size_t)(t0 + tc + 16)) * NDIM + n) * KDIM + kk] = pikB;
}

// ------- fallback: round-5 fused VI+policy (used if ws too small for q_ws) -------
__global__ __launch_bounds__(512) void vi_policy_kernel(
    const float* __restrict__ theta, const float* __restrict__ lse,
    const float* __restrict__ rws, const float* __restrict__ pdfg,
    const float* __restrict__ out_b_g, float* __restrict__ out_pi)
{
    __shared__ __align__(16) float q_s[HDIM * KDIM * 68];
    __shared__ float r_s[KDIM * SDIM];
    __shared__ float lse_s[KDIM * SDIM];
    __shared__ __align__(16) float v_s[SDIM];
    __shared__ __align__(16) float b_lds[64 * 68];
    __shared__ float pdf_s[32];

    const int n = blockIdx.x, tid = threadIdx.x;
    const int wave = tid >> 6, lane = tid & 63;
    const int sub = lane & 15, rq = lane >> 4;
    const float* Xn = theta + (size_t)n * NP + 4096;

    for (int idx = tid; idx < KDIM * SDIM; idx += 512) {
        r_s[idx]   = rws[(size_t)n * KDIM * SDIM + idx];
        lse_s[idx] = lse[(size_t)n * KDIM * SDIM + idx];
    }
    if (tid < HDIM) pdf_s[tid] = pdfg[n * HDIM + tid];
    __syncthreads();

    for (int idx = tid; idx < KDIM * SDIM; idx += 512)
        q_s[(idx >> 6) * 68 + (idx & 63)] = r_s[idx];

    float4 breg[32];
#pragma unroll
    for (int it = 0; it < 32; ++it) {
        const int row = it * 32 + wave * 4 + rq;
        const float* xr = Xn + (size_t)row * SDIM + sub * 4;
        const float l = lse_s[row];
        breg[it] = make_float4(__expf(xr[0] - l), __expf(xr[1] - l),
                               __expf(xr[2] - l), __expf(xr[3] - l));
    }
    bar_lds();

#pragma unroll 1
    for (int h = 1; h < HDIM; ++h) {
        if (tid < SDIM) {
            const int base = (h - 1) * KDIM;
            float m = -1e30f;
#pragma unroll
            for (int k = 0; k < KDIM; ++k) m = fmaxf(m, q_s[(base + k) * 68 + tid]);
            float ssum = 0.f;
#pragma unroll
            for (int k = 0; k < KDIM; ++k) ssum += __expf(q_s[(base + k) * 68 + tid] - m);
            v_s[tid] = m + __logf(ssum);
        }
        bar_lds();
        const float4 v4 = *(const float4*)&v_s[sub * 4];
#pragma unroll
        for (int it = 0; it < 32; ++it) {
            const int row = it * 32 + wave * 4 + rq;
            float acc = breg[it].x * v4.x + breg[it].y * v4.y
                      + breg[it].z * v4.z + breg[it].w * v4.w;
            acc += __shfl_xor(acc, 1, 64);
            acc += __shfl_xor(acc, 2, 64);
            acc += __shfl_xor(acc, 4, 64);
            acc += __shfl_xor(acc, 8, 64);
            if (sub == 0)
                q_s[(h * KDIM + (row >> 6)) * 68 + (row & 63)] = r_s[row] + acc;
        }
        bar_lds();
    }

    const int tc = tid >> 4, kk = tid & 15;
#pragma unroll 1
    for (int t0 = 0; t0 < TDIM; t0 += 64) {
        const int nt = (TDIM - t0) < 64 ? (TDIM - t0) : 64;
        for (int idx = tid; idx < nt * 16; idx += 512) {
            const int row = idx >> 4, jq = idx & 15;
            *(float4*)&b_lds[row * 68 + jq * 4] =
                *(const float4*)&out_b_g[(((size_t)(t0 + row)) * NDIM + n) * SDIM + jq * 4];
        }
        bar_lds();
        const bool vA = tc < nt, vB = (tc + 32) < nt;
        float4 bqA[16], bqB[16];
        if (vA) {
#pragma unroll
            for (int jq = 0; jq < 16; ++jq)
                bqA[jq] = *(const float4*)&b_lds[tc * 68 + jq * 4];
        }
        if (vB) {
#pragma unroll
            for (int jq = 0; jq < 16; ++jq)
                bqB[jq] = *(const float4*)&b_lds[(tc + 32) * 68 + jq * 4];
        }
        float pikA = 0.f, pikB = 0.f;
#pragma unroll 1
        for (int h = 0; h < HDIM; ++h) {
            const float* qr = &q_s[(h * KDIM + kk) * 68];
            float aA = 0.f, aB = 0.f;
#pragma unroll
            for (int jq = 0; jq < 16; ++jq) {
                const float4 qv = *(const float4*)&qr[jq * 4];
                if (vA) aA += qv.x * bqA[jq].x + qv.y * bqA[jq].y
                            + qv.z * bqA[jq].z + qv.w * bqA[jq].w;
                if (vB) aB += qv.x * bqB[jq].x + qv.y * bqB[jq].y
                            + qv.z * bqB[jq].z + qv.w * bqB[jq].w;
            }
            float mA = aA, mB = aB;
            mA = fmaxf(mA, __shfl_xor(mA, 1, 64));
            mA = fmaxf(mA, __shfl_xor(mA, 2, 64));
            mA = fmaxf(mA, __shfl_xor(mA, 4, 64));
            mA = fmaxf(mA, __shfl_xor(mA, 8, 64));
            mB = fmaxf(mB, __shfl_xor(mB, 1, 64));
            mB = fmaxf(mB, __shfl_xor(mB, 2, 64));
            mB = fmaxf(mB, __shfl_xor(mB, 4, 64));
            mB = fmaxf(mB, __shfl_xor(mB, 8, 64));
            float eA = __expf(aA - mA), eB = __expf(aB - mB);
            float SA = eA, SB = eB;
            SA += __shfl_xor(SA, 1, 64);
            SA += __shfl_xor(SA, 2, 64);
            SA += __shfl_xor(SA, 4, 64);
            SA += __shfl_xor(SA, 8, 64);
            SB += __shfl_xor(SB, 1, 64);
            SB += __shfl_xor(SB, 2, 64);
            SB += __shfl_xor(SB, 4, 64);
            SB += __shfl_xor(SB, 8, 64);
            const float ph = pdf_s[h];
            pikA += ph * eA / SA;
            pikB += ph * eB / SB;
        }
        if (vA) out_pi[(((size_t)(t0 + tc)) * NDIM + n) * KDIM + kk] = pikA;
        if (vB) out_pi[(((size_t)(t0 + 32 + tc)) * NDIM + n) * KDIM + kk] = pikB;
        bar_lds();
    }
}

extern "C" void kernel_launch(void* const* d_in, const int* in_sizes, int n_in,
                              void* d_out, int out_size, void* d_ws, size_t ws_size,
                              hipStream_t stream) {
    (void)in_sizes; (void)n_in; (void)out_size;
    const float* o     = (const float*)d_in[0];
    const int*   a     = (const int*)d_in[1];
    const float* theta = (const float*)d_in[2];
    float* out = (float*)d_out;
    float* ws  = (float*)d_ws;

    float* lse    = ws;                                   // N*K*S
    float* rws    = lse    + (size_t)NDIM * KDIM * SDIM;  // N*K*S
    float* invstd = rws    + (size_t)NDIM * KDIM * SDIM;  // N*S*O
    float* c0     = invstd + (size_t)NDIM * SDIM * ODIM;  // N*S
    float* ent    = c0     + (size_t)NDIM * SDIM;         // N*S
    float* logC   = ent    + (size_t)NDIM * SDIM;         // N*S
    float* Dws    = logC   + (size_t)NDIM * SDIM;         // N*S
    float* pdfws  = Dws    + (size_t)NDIM * SDIM;         // N*H
    float* q_ws   = pdfws  + (size_t)NDIM * HDIM;         // N*H*K*S (63 MB)

    const size_t base_floats = (size_t)NDIM * KDIM * SDIM * 2
                             + (size_t)NDIM * SDIM * ODIM
                             + (size_t)NDIM * SDIM * 4
                             + (size_t)NDIM * HDIM;
    const size_t need_bytes = (base_floats + (size_t)NDIM * HDIM * KDIM * SDIM) * 4;

    float* out_pi = out;
    float* out_b  = out + (size_t)TDIM * NDIM * KDIM;
    float* out_lp = out + (size_t)TDIM * NDIM * KDIM + (size_t)TDIM * NDIM * SDIM;

    transform_kernel<<<NDIM, 256, 0, stream>>>(theta, invstd, c0, ent, logC, Dws, pdfws);
    row_stats_kernel<<<(NDIM * KDIM * SDIM) / 4, 256, 0, stream>>>(theta, logC, ent, lse, rws);
    belief_kernel<<<NDIM, 512, 0, stream>>>(o, a, theta, lse, invstd, c0, Dws, out_b, out_lp);

    if (ws_size >= need_bytes) {
        vi_kernel<<<NDIM, 512, 0, stream>>>(theta, lse, rws, q_ws);
        dim3 pgrid((TDIM + 31) / 32, NDIM);
        policy_kernel<<<pgrid, 256, 0, stream>>>(q_ws, out_b, pdfws, out_pi);
    } else {
        vi_policy_kernel<<<NDIM, 512, 0, stream>>>(theta, lse, rws, pdfws, out_b, out_pi);
    }
}